// Round 2
// baseline (570.433 us; speedup 1.0000x reference)
//
#include <hip/hip_runtime.h>

typedef _Float16 h8v __attribute__((ext_vector_type(8)));
typedef float    f4v __attribute__((ext_vector_type(4)));

#define MFMA16(a,b,c) __builtin_amdgcn_mfma_f32_16x16x32_f16((a),(b),(c),0,0,0)
#define NEGF (-1e30f)

#define MEM 1000
#define KEY 64
#define VAL 128
#define DIN 512
#define BS  512
#define BQ  65536

__device__ __forceinline__ h8v cvt8(const float* p)
{
  float4 u = *(const float4*)p;
  float4 v = *(const float4*)(p + 4);
  h8v a;
  a[0] = (_Float16)u.x; a[1] = (_Float16)u.y; a[2] = (_Float16)u.z; a[3] = (_Float16)u.w;
  a[4] = (_Float16)v.x; a[5] = (_Float16)v.y; a[6] = (_Float16)v.z; a[7] = (_Float16)v.w;
  return a;
}

// ---------------------------------------------------------------------------
// prep1: fp16 transposed weights, combined Wck = baseW@kpW, bcomb, ranks, zero
// ---------------------------------------------------------------------------
__global__ void k_prep1(const float* __restrict__ baseW, const float* __restrict__ base_b,
                        const float* __restrict__ kpW, const float* __restrict__ kp_b,
                        const float* __restrict__ vpW, const float* __restrict__ c1W,
                        const float* __restrict__ c2W, const float* __restrict__ age,
                        _Float16* __restrict__ WT, float* __restrict__ bcomb,
                        _Float16* __restrict__ vpWt, _Float16* __restrict__ c1Wt,
                        _Float16* __restrict__ c2Wt, int* __restrict__ ranks,
                        float* __restrict__ out0)
{
  long id = (long)blockIdx.x * 256 + threadIdx.x;
  if (id < 32768) {                       // WT[n][k] = baseW[k][n]  (rows 0..63)
    long n = id >> 9, k = id & 511;
    WT[(size_t)n * 512 + k] = (_Float16)baseW[k * 64 + n];
  } else if (id < 65536) {                // WT[64+n][k] = Wck[k][n] = sum_j baseW[k][j] kpW[j][n]
    long i = id - 32768, n = i >> 9, k = i & 511;
    const float* br = baseW + k * 64;
    float s = 0.f;
    for (int j = 0; j < 64; ++j) s += br[j] * kpW[j * 64 + n];
    WT[(size_t)(64 + n) * 512 + k] = (_Float16)s;
  } else if (id < 65664) {                // bcomb[0..63]=base_b ; [64..127]=base_b@kpW+kp_b
    int i = (int)(id - 65536);
    if (i < 64) bcomb[i] = base_b[i];
    else {
      int n = i - 64;
      float s = kp_b[n];
      for (int j = 0; j < 64; ++j) s += base_b[j] * kpW[j * 64 + n];
      bcomb[i] = s;
    }
  } else if (id < 90240) {                // c1Wt[n][k], 128x192
    long i = id - 65664, n = i / 192, k = i % 192;
    c1Wt[i] = (_Float16)c1W[k * 128 + n];
  } else if (id < 98432) {                // c2Wt[n][k], 64x128
    long i = id - 90240, n = i >> 7, k = i & 127;
    c2Wt[i] = (_Float16)c2W[k * 64 + n];
  } else if (id < 114816) {               // vpWt[n][k], 128x128
    long i = id - 98432, n = i >> 7, k = i & 127;
    vpWt[i] = (_Float16)vpW[k * 128 + n];
  } else if (id < 115816) {               // stable ranks (lax.top_k order)
    int j = (int)(id - 114816);
    float aj = age[j];
    int r = 0;
    for (int i2 = 0; i2 < MEM; ++i2) {
      float ai = age[i2];
      r += (ai > aj) || (ai == aj && i2 < j);
    }
    ranks[j] = r;
  } else if (id == 115816) {
    *out0 = 0.f;
  }
}

// ---------------------------------------------------------------------------
// prep2: pkeys = sx@Wck + bck ; pvals = sy@vpW + vp_b   (MFMA, 16 rows/wave)
// ---------------------------------------------------------------------------
__global__ __launch_bounds__(64) void k_prep2(
    const float* __restrict__ sx, const float* __restrict__ sy,
    const _Float16* __restrict__ WT, const float* __restrict__ bcomb,
    const _Float16* __restrict__ vpWt, const float* __restrict__ vp_b,
    float* __restrict__ pkeys, float* __restrict__ pvals)
{
  const int lane = threadIdx.x, quad = lane >> 4, l15 = lane & 15;
  const f4v fz = {0.f, 0.f, 0.f, 0.f};
  if (blockIdx.x < 32) {
    const int m0 = blockIdx.x * 16;
    f4v acc[4];
    #pragma unroll
    for (int f = 0; f < 4; ++f) acc[f] = fz;
    const float* xr = sx + (size_t)(m0 + l15) * DIN;
    #pragma unroll 4
    for (int ks = 0; ks < 16; ++ks) {
      int k0 = ks * 32 + quad * 8;
      h8v a = cvt8(xr + k0);
      #pragma unroll
      for (int f = 0; f < 4; ++f) {
        h8v b = *(const h8v*)(WT + (size_t)(64 + f * 16 + l15) * 512 + k0);
        acc[f] = MFMA16(a, b, acc[f]);
      }
    }
    #pragma unroll
    for (int f = 0; f < 4; ++f) {
      int col = f * 16 + l15;
      float bb = bcomb[64 + col];
      #pragma unroll
      for (int r = 0; r < 4; ++r)
        pkeys[(size_t)(m0 + quad * 4 + r) * KEY + col] = acc[f][r] + bb;
    }
  } else {
    const int m0 = (blockIdx.x - 32) * 16;
    f4v acc[8];
    #pragma unroll
    for (int f = 0; f < 8; ++f) acc[f] = fz;
    const float* yr = sy + (size_t)(m0 + l15) * VAL;
    #pragma unroll
    for (int ks = 0; ks < 4; ++ks) {
      int k0 = ks * 32 + quad * 8;
      h8v a = cvt8(yr + k0);
      #pragma unroll
      for (int f = 0; f < 8; ++f) {
        h8v b = *(const h8v*)(vpWt + (size_t)(f * 16 + l15) * 128 + k0);
        acc[f] = MFMA16(a, b, acc[f]);
      }
    }
    #pragma unroll
    for (int f = 0; f < 8; ++f) {
      int col = f * 16 + l15;
      float bb = vp_b[col];
      #pragma unroll
      for (int r = 0; r < 4; ++r)
        pvals[(size_t)(m0 + quad * 4 + r) * VAL + col] = acc[f][r] + bb;
    }
  }
}

// ---------------------------------------------------------------------------
// prep3: scatter into keysH [1024][64] fp16 and valT [128][1024] fp16 (zero-pad)
// ---------------------------------------------------------------------------
__global__ void k_prep3(const int* __restrict__ ranks, const float* __restrict__ pk,
                        const float* __restrict__ pv, const float* __restrict__ memK,
                        const float* __restrict__ memV,
                        _Float16* __restrict__ keysH, _Float16* __restrict__ valT)
{
  const int b = blockIdx.x, t = threadIdx.x;
  if (b < 1024) {
    float v = 0.f;
    if (b < MEM) {
      int rk = ranks[b];
      v = (rk < BS) ? pk[(size_t)rk * KEY + t] : memK[(size_t)b * KEY + t];
    }
    keysH[(size_t)b * KEY + t] = (_Float16)v;
  } else {
    int i = b - 1024;
    int n = i >> 2, jb = (i & 3) * 256;
    for (int it = 0; it < 4; ++it) {
      int j = jb + it * 64 + t;
      float v = 0.f;
      if (j < MEM) {
        int rk = ranks[j];
        v = (rk < BS) ? pv[(size_t)rk * VAL + n] : memV[(size_t)j * VAL + n];
      }
      valT[(size_t)n * 1024 + j] = (_Float16)v;
    }
  }
}

// ---------------------------------------------------------------------------
// feat: qfpq[65536][128] fp16 = qx @ [baseW | Wck] + bcomb   (streaming GEMM)
// ---------------------------------------------------------------------------
__global__ __launch_bounds__(64) void k_feat(const float* __restrict__ qx,
                                             const _Float16* __restrict__ WT,
                                             const float* __restrict__ bcomb,
                                             _Float16* __restrict__ qfpq)
{
  const int lane = threadIdx.x, quad = lane >> 4, l15 = lane & 15;
  const int q0 = blockIdx.x * 32;
  const f4v fz = {0.f, 0.f, 0.f, 0.f};
  f4v acc[2][8];
  #pragma unroll
  for (int rt = 0; rt < 2; ++rt)
    #pragma unroll
    for (int f = 0; f < 8; ++f) acc[rt][f] = fz;

  const float* xr0 = qx + (size_t)(q0 + l15) * DIN;
  const float* xr1 = qx + (size_t)(q0 + 16 + l15) * DIN;

  #pragma unroll 4
  for (int ks = 0; ks < 16; ++ks) {
    const int k0 = ks * 32 + quad * 8;
    h8v a0 = cvt8(xr0 + k0);
    h8v a1 = cvt8(xr1 + k0);
    #pragma unroll
    for (int f = 0; f < 8; ++f) {
      h8v b = *(const h8v*)(WT + (size_t)(f * 16 + l15) * 512 + k0);
      acc[0][f] = MFMA16(a0, b, acc[0][f]);
      acc[1][f] = MFMA16(a1, b, acc[1][f]);
    }
  }
  #pragma unroll
  for (int f = 0; f < 8; ++f) {
    int col = f * 16 + l15;
    float bb = bcomb[col];
    #pragma unroll
    for (int rt = 0; rt < 2; ++rt)
      #pragma unroll
      for (int r = 0; r < 4; ++r)
        qfpq[(size_t)(q0 + rt * 16 + quad * 4 + r) * 128 + col] =
            (_Float16)(acc[rt][f][r] + bb);
  }
}

// ---------------------------------------------------------------------------
// main: fused attention + controller. 1 wave / 32 queries. LDS 17408 B ->
// 9 blocks/CU (full residency at grid 2048 = 8/CU).
// ---------------------------------------------------------------------------
__global__ __launch_bounds__(64) void k_main(
    const _Float16* __restrict__ qfpq, const float* __restrict__ qy,
    const float* __restrict__ c1_b, const float* __restrict__ c2_b,
    const float* __restrict__ c3W, const float* __restrict__ c3b,
    const _Float16* __restrict__ c1Wt, const _Float16* __restrict__ c2Wt,
    const _Float16* __restrict__ keysH, const _Float16* __restrict__ valT,
    float* __restrict__ dout)
{
  // overlays: P -> ret -> h1 share one buffer (in-order DS, per-half in-place);
  // h2 overlays qf tile (dead after c1).
  __shared__ __align__(16) char smem[17408];
  _Float16* qf_s = (_Float16*)smem;            // 32 x 136 : cols 0..63 qf, 64..127 pq
  _Float16* P_s  = (_Float16*)(smem + 8704);   // 32 x 136 : P / ret / h1
  _Float16* h2_s = (_Float16*)smem;            // 32 x 72  : overlays qf region

  const int lane = threadIdx.x;
  const int quad = lane >> 4;
  const int l15  = lane & 15;
  const int q0   = blockIdx.x * 32;

  float* out_pred = dout + 1;
  float* out_ret  = dout + 1 + BQ;
  const f4v fz = {0.f, 0.f, 0.f, 0.f};

  // ---- prologue: load 32x128 fp16 tile into padded LDS ----
  const _Float16* qt = qfpq + (size_t)q0 * 128;
  #pragma unroll
  for (int i = 0; i < 8; ++i) {
    int o = i * 512 + lane * 8;                // halves
    h8v v = *(const h8v*)(qt + o);
    *(h8v*)&qf_s[(o >> 7) * 136 + (o & 127)] = v;
  }

  // ---- attention: online softmax over 8 chunks of 128 mem slots ----
  float rm[2][4], rl[2][4];
  #pragma unroll
  for (int rt = 0; rt < 2; ++rt)
    #pragma unroll
    for (int r = 0; r < 4; ++r) { rm[rt][r] = NEGF; rl[rt][r] = 0.f; }

  f4v O[2][8];
  #pragma unroll
  for (int rt = 0; rt < 2; ++rt)
    #pragma unroll
    for (int v = 0; v < 8; ++v) O[rt][v] = fz;

  #pragma unroll 1
  for (int c = 0; c < 8; ++c) {
    #pragma unroll 1
    for (int rt = 0; rt < 2; ++rt) {
      f4v S[8];
      #pragma unroll
      for (int f = 0; f < 8; ++f) S[f] = fz;

      #pragma unroll
      for (int ks = 0; ks < 2; ++ks) {
        const int k0 = ks * 32 + quad * 8;
        h8v a = *(const h8v*)&qf_s[(rt * 16 + l15) * 136 + 64 + k0];  // pq cols
        #pragma unroll
        for (int f = 0; f < 8; ++f) {
          h8v b = *(const h8v*)(keysH + (size_t)(c * 128 + f * 16 + l15) * KEY + k0);
          S[f] = MFMA16(a, b, S[f]);
        }
      }
      float cm[4] = {NEGF, NEGF, NEGF, NEGF};
      #pragma unroll
      for (int f = 0; f < 8; ++f) {
        const int col = c * 128 + f * 16 + l15;
        const bool ok = (col < MEM);
        #pragma unroll
        for (int r = 0; r < 4; ++r) {
          float s = ok ? S[f][r] : NEGF;
          S[f][r] = s;
          cm[r] = fmaxf(cm[r], s);
        }
      }
      #pragma unroll
      for (int r = 0; r < 4; ++r) {
        #pragma unroll
        for (int m = 1; m < 16; m <<= 1) cm[r] = fmaxf(cm[r], __shfl_xor(cm[r], m));
      }
      float al[4], ps[4] = {0.f, 0.f, 0.f, 0.f};
      #pragma unroll
      for (int r = 0; r < 4; ++r) {
        float mn = fmaxf(rm[rt][r], cm[r]);
        al[r] = __expf(rm[rt][r] - mn);
        rm[rt][r] = mn;
      }
      #pragma unroll
      for (int f = 0; f < 8; ++f)
        #pragma unroll
        for (int r = 0; r < 4; ++r) {
          float p = __expf(S[f][r] - rm[rt][r]);
          S[f][r] = p;
          ps[r] += p;
        }
      #pragma unroll
      for (int r = 0; r < 4; ++r) {
        #pragma unroll
        for (int m = 1; m < 16; m <<= 1) ps[r] += __shfl_xor(ps[r], m);
        rl[rt][r] = rl[rt][r] * al[r] + ps[r];
      }
      #pragma unroll
      for (int f = 0; f < 8; ++f)
        #pragma unroll
        for (int r = 0; r < 4; ++r)
          P_s[(rt * 16 + quad * 4 + r) * 136 + f * 16 + l15] = (_Float16)S[f][r];
      #pragma unroll
      for (int v = 0; v < 8; ++v)
        #pragma unroll
        for (int r = 0; r < 4; ++r) O[rt][v][r] *= al[r];
    }
    #pragma unroll
    for (int ks = 0; ks < 4; ++ks) {
      const int k0 = ks * 32 + quad * 8;
      h8v a0 = *(const h8v*)&P_s[l15 * 136 + k0];
      h8v a1 = *(const h8v*)&P_s[(16 + l15) * 136 + k0];
      #pragma unroll
      for (int v = 0; v < 8; ++v) {
        h8v b = *(const h8v*)(valT + (size_t)(v * 16 + l15) * 1024 + c * 128 + k0);
        O[0][v] = MFMA16(a0, b, O[0][v]);
        O[1][v] = MFMA16(a1, b, O[1][v]);
      }
    }
  }

  // ---- retrieved: global fp32 + fp16 into P_s (P dead -> ret) ----
  #pragma unroll
  for (int rt = 0; rt < 2; ++rt)
    #pragma unroll
    for (int v = 0; v < 8; ++v)
      #pragma unroll
      for (int r = 0; r < 4; ++r) {
        int row = rt * 16 + quad * 4 + r;
        int col = v * 16 + l15;
        float val = O[rt][v][r] / rl[rt][r];
        out_ret[(size_t)(q0 + row) * VAL + col] = val;
        P_s[row * 136 + col] = (_Float16)val;
      }

  // ---- c1: relu([qf|ret] @ c1_W + b), h1 overwrites ret in place per-half ----
  #pragma unroll 1
  for (int rt = 0; rt < 2; ++rt) {
    f4v H[8];
    #pragma unroll
    for (int f = 0; f < 8; ++f) H[f] = fz;
    #pragma unroll
    for (int ks = 0; ks < 6; ++ks) {
      const int k0 = ks * 32 + quad * 8;
      h8v a = (k0 < 64) ? *(const h8v*)&qf_s[(rt * 16 + l15) * 136 + k0]
                        : *(const h8v*)&P_s[(rt * 16 + l15) * 136 + (k0 - 64)];
      #pragma unroll
      for (int f = 0; f < 8; ++f) {
        h8v b = *(const h8v*)(c1Wt + (size_t)(f * 16 + l15) * 192 + k0);
        H[f] = MFMA16(a, b, H[f]);
      }
    }
    #pragma unroll
    for (int f = 0; f < 8; ++f) {
      float bb = c1_b[f * 16 + l15];
      #pragma unroll
      for (int r = 0; r < 4; ++r)
        P_s[(rt * 16 + quad * 4 + r) * 136 + f * 16 + l15] =
            (_Float16)fmaxf(0.f, H[f][r] + bb);
    }
  }

  // ---- c2: relu(h1 @ c2_W + b) -> h2 (overlays dead qf tile) ----
  #pragma unroll 1
  for (int rt = 0; rt < 2; ++rt) {
    f4v G[4];
    #pragma unroll
    for (int f = 0; f < 4; ++f) G[f] = fz;
    #pragma unroll
    for (int ks = 0; ks < 4; ++ks) {
      const int k0 = ks * 32 + quad * 8;
      h8v a = *(const h8v*)&P_s[(rt * 16 + l15) * 136 + k0];
      #pragma unroll
      for (int f = 0; f < 4; ++f) {
        h8v b = *(const h8v*)(c2Wt + (size_t)(f * 16 + l15) * 128 + k0);
        G[f] = MFMA16(a, b, G[f]);
      }
    }
    #pragma unroll
    for (int f = 0; f < 4; ++f) {
      float bb = c2_b[f * 16 + l15];
      #pragma unroll
      for (int r = 0; r < 4; ++r)
        h2_s[(rt * 16 + quad * 4 + r) * 72 + f * 16 + l15] =
            (_Float16)fmaxf(0.f, G[f][r] + bb);
    }
  }

  // ---- c3 + loss ----
  const int prow = lane >> 1, pj = lane & 1;
  float s = 0.f;
  #pragma unroll
  for (int k = 0; k < 32; ++k) {
    int kk = pj * 32 + k;
    s += (float)h2_s[prow * 72 + kk] * c3W[kk];
  }
  s += __shfl_xor(s, 1);
  float pred = s + c3b[0];
  float diff = pred - qy[q0 + prow];
  if (pj == 0) out_pred[q0 + prow] = pred;
  float sq = diff * diff;                      // each row counted twice
  #pragma unroll
  for (int m = 1; m < 64; m <<= 1) sq += __shfl_xor(sq, m);
  if (lane == 0) atomicAdd(dout, sq * (1.0f / (2.0f * (float)BQ)));
}

// ---------------------------------------------------------------------------
extern "C" void kernel_launch(void* const* d_in, const int* in_sizes, int n_in,
                              void* d_out, int out_size, void* d_ws, size_t ws_size,
                              hipStream_t stream)
{
  const float* support_x = (const float*)d_in[0];
  const float* support_y = (const float*)d_in[1];
  const float* query_x   = (const float*)d_in[2];
  const float* query_y   = (const float*)d_in[3];
  const float* base_W    = (const float*)d_in[4];
  const float* base_b    = (const float*)d_in[5];
  const float* kp_W      = (const float*)d_in[6];
  const float* kp_b      = (const float*)d_in[7];
  const float* vp_W      = (const float*)d_in[8];
  const float* vp_b      = (const float*)d_in[9];
  const float* mem_keys  = (const float*)d_in[10];
  const float* mem_vals  = (const float*)d_in[11];
  const float* mem_age   = (const float*)d_in[12];
  const float* c1_W      = (const float*)d_in[13];
  const float* c1_b      = (const float*)d_in[14];
  const float* c2_W      = (const float*)d_in[15];
  const float* c2_b      = (const float*)d_in[16];
  const float* c3_W      = (const float*)d_in[17];
  const float* c3_b      = (const float*)d_in[18];

  char* w = (char*)d_ws;                        // ~17.8 MB used
  _Float16* WT    = (_Float16*)(w + 0);         // 128x512 fp16 [baseW^T | Wck^T]
  _Float16* vpWt  = (_Float16*)(w + 131072);    // 128x128
  _Float16* c1Wt  = (_Float16*)(w + 163840);    // 128x192
  _Float16* c2Wt  = (_Float16*)(w + 212992);    // 64x128
  float*    bcomb = (float*)   (w + 229376);    // 128 f32
  int*      ranks = (int*)     (w + 229888);    // 1000 i32
  float*    pkeys = (float*)   (w + 233984);    // 512x64 f32
  float*    pvals = (float*)   (w + 365056);    // 512x128 f32
  _Float16* keysH = (_Float16*)(w + 627200);    // 1024x64 (zero-padded)
  _Float16* valT  = (_Float16*)(w + 758272);    // 128x1024 (zero-padded)
  _Float16* qfpq  = (_Float16*)(w + 1048576);   // 65536x128 fp16

  float* out = (float*)d_out;

  hipLaunchKernelGGL(k_prep1, dim3(453), dim3(256), 0, stream,
                     base_W, base_b, kp_W, kp_b, vp_W, c1_W, c2_W, mem_age,
                     WT, bcomb, vpWt, c1Wt, c2Wt, ranks, out);
  hipLaunchKernelGGL(k_prep2, dim3(64), dim3(64), 0, stream,
                     support_x, support_y, WT, bcomb, vpWt, vp_b, pkeys, pvals);
  hipLaunchKernelGGL(k_prep3, dim3(1536), dim3(64), 0, stream,
                     ranks, pkeys, pvals, mem_keys, mem_vals, keysH, valT);
  hipLaunchKernelGGL(k_feat, dim3(BQ / 32), dim3(64), 0, stream,
                     query_x, WT, bcomb, qfpq);
  hipLaunchKernelGGL(k_main, dim3(BQ / 32), dim3(64), 0, stream,
                     qfpq, query_y, c1_b, c2_b, c3_W, c3_b,
                     c1Wt, c2Wt, keysH, valT, out);
}

// Round 3
// 558.688 us; speedup vs baseline: 1.0210x; 1.0210x over previous
//
#include <hip/hip_runtime.h>

typedef _Float16 h8v __attribute__((ext_vector_type(8)));
typedef float    f4v __attribute__((ext_vector_type(4)));

#define MFMA16(a,b,c) __builtin_amdgcn_mfma_f32_16x16x32_f16((a),(b),(c),0,0,0)
#define NEGF (-1e30f)

#define MEM 1000
#define KEY 64
#define VAL 128
#define DIN 512
#define BS  512
#define BQ  65536

// Fragment-major B layouts: element (F,KS,lane,j) at ((F*nKS+KS)*64+lane)*8+j
// holds B[n = F*16 + (lane&15)][k = KS*32 + (lane>>4)*8 + j]  -> every MFMA
// B-fragment load is lane-contiguous (16 B/lane, 1 KB/wave, 8 full lines).

__device__ __forceinline__ h8v cvt8(const float* p)
{
  float4 u = *(const float4*)p;
  float4 v = *(const float4*)(p + 4);
  h8v a;
  a[0] = (_Float16)u.x; a[1] = (_Float16)u.y; a[2] = (_Float16)u.z; a[3] = (_Float16)u.w;
  a[4] = (_Float16)v.x; a[5] = (_Float16)v.y; a[6] = (_Float16)v.z; a[7] = (_Float16)v.w;
  return a;
}

// ---------------------------------------------------------------------------
// prep1: fragment-major weights, Wck = baseW@kpW fused, bcomb, ranks, zero
// ---------------------------------------------------------------------------
__global__ void k_prep1(const float* __restrict__ baseW, const float* __restrict__ base_b,
                        const float* __restrict__ kpW, const float* __restrict__ kp_b,
                        const float* __restrict__ vpW, const float* __restrict__ c1W,
                        const float* __restrict__ c2W, const float* __restrict__ age,
                        _Float16* __restrict__ WTf, float* __restrict__ bcomb,
                        _Float16* __restrict__ vpWt, _Float16* __restrict__ c1F,
                        _Float16* __restrict__ c2F, int* __restrict__ ranks,
                        float* __restrict__ out0)
{
  long id = (long)blockIdx.x * 256 + threadIdx.x;
  if (id < 65536) {                        // WTf: [baseW^T | Wck^T], n=128, k=512 (KS=16)
    int h = (int)id;
    int j = h & 7, lane = (h >> 3) & 63, KS = (h >> 9) & 15, F = h >> 13;
    int n = F * 16 + (lane & 15);
    int k = KS * 32 + ((lane >> 4) << 3) + j;
    float v;
    if (n < 64) v = baseW[(size_t)k * 64 + n];
    else {
      int nn = n - 64;
      const float* br = baseW + (size_t)k * 64;
      float s = 0.f;
      for (int t = 0; t < 64; ++t) s += br[t] * kpW[t * 64 + nn];
      v = s;
    }
    WTf[h] = (_Float16)v;
  } else if (id < 65664) {                 // bcomb
    int i = (int)(id - 65536);
    if (i < 64) bcomb[i] = base_b[i];
    else {
      int n = i - 64;
      float s = kp_b[n];
      for (int t = 0; t < 64; ++t) s += base_b[t] * kpW[t * 64 + n];
      bcomb[i] = s;
    }
  } else if (id < 90240) {                 // c1F: n=128 (F=8), k=192 (KS=6)
    int h = (int)(id - 65664);
    int j = h & 7, lane = (h >> 3) & 63, KS = (h >> 9) % 6, F = (h >> 9) / 6;
    int n = F * 16 + (lane & 15);
    int k = KS * 32 + ((lane >> 4) << 3) + j;
    c1F[h] = (_Float16)c1W[(size_t)k * 128 + n];
  } else if (id < 98432) {                 // c2F: n=64 (F=4), k=128 (KS=4)
    int h = (int)(id - 90240);
    int j = h & 7, lane = (h >> 3) & 63, KS = (h >> 9) & 3, F = h >> 11;
    int n = F * 16 + (lane & 15);
    int k = KS * 32 + ((lane >> 4) << 3) + j;
    c2F[h] = (_Float16)c2W[(size_t)k * 64 + n];
  } else if (id < 114816) {                // vpWt[n][k] (row-major transposed, prep2 only)
    long i = id - 98432;
    int n = (int)(i >> 7), k = (int)(i & 127);
    vpWt[i] = (_Float16)vpW[(size_t)k * 128 + n];
  } else if (id < 115816) {                // stable ranks (lax.top_k order)
    int jx = (int)(id - 114816);
    float aj = age[jx];
    int r = 0;
    for (int i2 = 0; i2 < MEM; ++i2) {
      float ai = age[i2];
      r += (ai > aj) || (ai == aj && i2 < jx);
    }
    ranks[jx] = r;
  } else if (id == 115816) {
    *out0 = 0.f;
  }
}

// ---------------------------------------------------------------------------
// prep2: pkeys = sx@Wck + bck ; pvals = sy@vpW + vp_b
// ---------------------------------------------------------------------------
__global__ __launch_bounds__(64) void k_prep2(
    const float* __restrict__ sx, const float* __restrict__ sy,
    const _Float16* __restrict__ WTf, const float* __restrict__ bcomb,
    const _Float16* __restrict__ vpWt, const float* __restrict__ vp_b,
    float* __restrict__ pkeys, float* __restrict__ pvals)
{
  const int lane = threadIdx.x, quad = lane >> 4, l15 = lane & 15;
  const f4v fz = {0.f, 0.f, 0.f, 0.f};
  if (blockIdx.x < 32) {
    const int m0 = blockIdx.x * 16;
    f4v acc[4];
    #pragma unroll
    for (int f = 0; f < 4; ++f) acc[f] = fz;
    const float* xr = sx + (size_t)(m0 + l15) * DIN;
    #pragma unroll 4
    for (int ks = 0; ks < 16; ++ks) {
      int k0 = ks * 32 + quad * 8;
      h8v a = cvt8(xr + k0);
      #pragma unroll
      for (int f = 0; f < 4; ++f) {
        h8v b = *(const h8v*)(WTf + (size_t)((((4 + f) * 16) + ks) * 64 + lane) * 8);
        acc[f] = MFMA16(a, b, acc[f]);
      }
    }
    #pragma unroll
    for (int f = 0; f < 4; ++f) {
      int col = f * 16 + l15;
      float bb = bcomb[64 + col];
      #pragma unroll
      for (int r = 0; r < 4; ++r)
        pkeys[(size_t)(m0 + quad * 4 + r) * KEY + col] = acc[f][r] + bb;
    }
  } else {
    const int m0 = (blockIdx.x - 32) * 16;
    f4v acc[8];
    #pragma unroll
    for (int f = 0; f < 8; ++f) acc[f] = fz;
    const float* yr = sy + (size_t)(m0 + l15) * VAL;
    #pragma unroll
    for (int ks = 0; ks < 4; ++ks) {
      int k0 = ks * 32 + quad * 8;
      h8v a = cvt8(yr + k0);
      #pragma unroll
      for (int f = 0; f < 8; ++f) {
        h8v b = *(const h8v*)(vpWt + (size_t)(f * 16 + l15) * 128 + k0);
        acc[f] = MFMA16(a, b, acc[f]);
      }
    }
    #pragma unroll
    for (int f = 0; f < 8; ++f) {
      int col = f * 16 + l15;
      float bb = vp_b[col];
      #pragma unroll
      for (int r = 0; r < 4; ++r)
        pvals[(size_t)(m0 + quad * 4 + r) * VAL + col] = acc[f][r] + bb;
    }
  }
}

// ---------------------------------------------------------------------------
// prep3: scatter memory into fragment-major keysF / valF (zero-padded)
// keysF: n=1024 slots (F=64), k=KEY 64 (KS=2)
// valF : n=VAL 128 (F=8),     k=1024 slots (KS=32)
// ---------------------------------------------------------------------------
__global__ void k_prep3(const int* __restrict__ ranks, const float* __restrict__ pk,
                        const float* __restrict__ pv, const float* __restrict__ memK,
                        const float* __restrict__ memV,
                        _Float16* __restrict__ keysF, _Float16* __restrict__ valF)
{
  int id = blockIdx.x * 256 + threadIdx.x;
  if (id < 65536) {
    int j = id & 7, lane = (id >> 3) & 63, KS = (id >> 9) & 1, F = id >> 10;
    int n = F * 16 + (lane & 15);                  // mem slot
    int k = KS * 32 + ((lane >> 4) << 3) + j;      // key col
    float v = 0.f;
    if (n < MEM) {
      int rk = ranks[n];
      v = (rk < BS) ? pk[(size_t)rk * KEY + k] : memK[(size_t)n * KEY + k];
    }
    keysF[id] = (_Float16)v;
  } else {
    int h = id - 65536;
    int j = h & 7, lane = (h >> 3) & 63, KS = (h >> 9) & 31, F = h >> 14;
    int nv = F * 16 + (lane & 15);                 // val col
    int jm = KS * 32 + ((lane >> 4) << 3) + j;     // mem slot
    float v = 0.f;
    if (jm < MEM) {
      int rk = ranks[jm];
      v = (rk < BS) ? pv[(size_t)rk * VAL + nv] : memV[(size_t)jm * VAL + nv];
    }
    valF[h] = (_Float16)v;
  }
}

// ---------------------------------------------------------------------------
// feat: qfpq[65536][128] fp16 = qx @ [baseW | Wck] + bcomb
// ---------------------------------------------------------------------------
__global__ __launch_bounds__(64, 3) void k_feat(const float* __restrict__ qx,
                                                const _Float16* __restrict__ WTf,
                                                const float* __restrict__ bcomb,
                                                _Float16* __restrict__ qfpq)
{
  const int lane = threadIdx.x, quad = lane >> 4, l15 = lane & 15;
  const int q0 = blockIdx.x * 32;
  const f4v fz = {0.f, 0.f, 0.f, 0.f};
  f4v acc[2][8];
  #pragma unroll
  for (int rt = 0; rt < 2; ++rt)
    #pragma unroll
    for (int f = 0; f < 8; ++f) acc[rt][f] = fz;

  const float* xr0 = qx + (size_t)(q0 + l15) * DIN;
  const float* xr1 = qx + (size_t)(q0 + 16 + l15) * DIN;

  #pragma unroll 4
  for (int ks = 0; ks < 16; ++ks) {
    const int k0 = ks * 32 + quad * 8;
    h8v a0 = cvt8(xr0 + k0);
    h8v a1 = cvt8(xr1 + k0);
    #pragma unroll
    for (int f = 0; f < 8; ++f) {
      h8v b = *(const h8v*)(WTf + (size_t)((f * 16 + ks) * 64 + lane) * 8);
      acc[0][f] = MFMA16(a0, b, acc[0][f]);
      acc[1][f] = MFMA16(a1, b, acc[1][f]);
    }
  }
  #pragma unroll
  for (int f = 0; f < 8; ++f) {
    int col = f * 16 + l15;
    float bb = bcomb[col];
    #pragma unroll
    for (int rt = 0; rt < 2; ++rt)
      #pragma unroll
      for (int r = 0; r < 4; ++r)
        qfpq[(size_t)(q0 + rt * 16 + quad * 4 + r) * 128 + col] =
            (_Float16)(acc[rt][f][r] + bb);
  }
}

// ---------------------------------------------------------------------------
// main: fused attention + controller, rt-outer (16 query rows per pass).
// Live state per pass <= ~110 VGPR; launch_bounds(64,3) guarantees no spill.
// LDS 6656 B. All global B-loads fragment-major coalesced.
// ---------------------------------------------------------------------------
__global__ __launch_bounds__(64, 3) void k_main(
    const _Float16* __restrict__ qfpq, const float* __restrict__ qy,
    const float* __restrict__ c1_b, const float* __restrict__ c2_b,
    const float* __restrict__ c3W, const float* __restrict__ c3b,
    const _Float16* __restrict__ c1F, const _Float16* __restrict__ c2F,
    const _Float16* __restrict__ keysF, const _Float16* __restrict__ valF,
    float* __restrict__ dout)
{
  __shared__ __align__(16) char smem[6656];
  _Float16* P_s  = (_Float16*)smem;            // 16 x 136 : P / ret / h1 overlay
  _Float16* h2_s = (_Float16*)(smem + 4352);   // 16 x 72

  const int lane = threadIdx.x;
  const int quad = lane >> 4;
  const int l15  = lane & 15;
  const int q0   = blockIdx.x * 32;

  float* out_pred = dout + 1;
  float* out_ret  = dout + 1 + BQ;
  const f4v fz = {0.f, 0.f, 0.f, 0.f};

  float lsum = 0.f;

  #pragma unroll 1
  for (int rt = 0; rt < 2; ++rt) {
    const int r0 = q0 + rt * 16;                 // first query row this pass
    const _Float16* qrow = qfpq + (size_t)(r0 + l15) * 128;

    // pq A-fragments (cols 64..127), direct in A-layout
    h8v pq0 = *(const h8v*)(qrow + 64 + quad * 8);
    h8v pq1 = *(const h8v*)(qrow + 96 + quad * 8);

    // ---- attention: online softmax over 8 chunks of 128 mem slots ----
    float rm[4], rl[4];
    #pragma unroll
    for (int r = 0; r < 4; ++r) { rm[r] = NEGF; rl[r] = 0.f; }
    f4v O[8];
    #pragma unroll
    for (int v = 0; v < 8; ++v) O[v] = fz;

    #pragma unroll 1
    for (int c = 0; c < 8; ++c) {
      f4v S[8];
      #pragma unroll
      for (int f = 0; f < 8; ++f) S[f] = fz;
      #pragma unroll
      for (int f = 0; f < 8; ++f) {
        const int F = c * 8 + f;
        h8v b0 = *(const h8v*)(keysF + (size_t)((F * 2 + 0) * 64 + lane) * 8);
        h8v b1 = *(const h8v*)(keysF + (size_t)((F * 2 + 1) * 64 + lane) * 8);
        S[f] = MFMA16(pq0, b0, S[f]);
        S[f] = MFMA16(pq1, b1, S[f]);
      }
      // mask pad cols + chunk row-max
      float cm[4] = {NEGF, NEGF, NEGF, NEGF};
      #pragma unroll
      for (int f = 0; f < 8; ++f) {
        const int col = c * 128 + f * 16 + l15;
        const bool ok = (col < MEM);
        #pragma unroll
        for (int r = 0; r < 4; ++r) {
          float s = ok ? S[f][r] : NEGF;
          S[f][r] = s;
          cm[r] = fmaxf(cm[r], s);
        }
      }
      #pragma unroll
      for (int r = 0; r < 4; ++r) {
        #pragma unroll
        for (int m = 1; m < 16; m <<= 1) cm[r] = fmaxf(cm[r], __shfl_xor(cm[r], m));
      }
      float al[4], ps[4] = {0.f, 0.f, 0.f, 0.f};
      #pragma unroll
      for (int r = 0; r < 4; ++r) {
        float mn = fmaxf(rm[r], cm[r]);
        al[r] = __expf(rm[r] - mn);
        rm[r] = mn;
      }
      #pragma unroll
      for (int f = 0; f < 8; ++f)
        #pragma unroll
        for (int r = 0; r < 4; ++r) {
          float p = __expf(S[f][r] - rm[r]);
          S[f][r] = p;
          ps[r] += p;
        }
      #pragma unroll
      for (int r = 0; r < 4; ++r) {
        #pragma unroll
        for (int m = 1; m < 16; m <<= 1) ps[r] += __shfl_xor(ps[r], m);
        rl[r] = rl[r] * al[r] + ps[r];
      }
      // P -> LDS (C-layout -> A-layout round trip), rescale O
      #pragma unroll
      for (int f = 0; f < 8; ++f)
        #pragma unroll
        for (int r = 0; r < 4; ++r)
          P_s[(quad * 4 + r) * 136 + f * 16 + l15] = (_Float16)S[f][r];
      #pragma unroll
      for (int v = 0; v < 8; ++v)
        #pragma unroll
        for (int r = 0; r < 4; ++r) O[v][r] *= al[r];
      // P @ V
      #pragma unroll
      for (int ks = 0; ks < 4; ++ks) {
        const int k0 = ks * 32 + quad * 8;
        h8v a = *(const h8v*)&P_s[l15 * 136 + k0];
        #pragma unroll
        for (int v = 0; v < 8; ++v) {
          h8v b = *(const h8v*)(valF + (size_t)((v * 32 + c * 4 + ks) * 64 + lane) * 8);
          O[v] = MFMA16(a, b, O[v]);
        }
      }
    }

    // ---- retrieved -> global fp32 + LDS fp16 (P dead -> ret) ----
    #pragma unroll
    for (int v = 0; v < 8; ++v)
      #pragma unroll
      for (int r = 0; r < 4; ++r) {
        int row = quad * 4 + r;
        int col = v * 16 + l15;
        float val = O[v][r] / rl[r];
        out_ret[(size_t)(r0 + row) * VAL + col] = val;
        P_s[row * 136 + col] = (_Float16)val;
      }

    // ---- c1: relu([qf|ret] @ c1_W + b); h1 overwrites ret in place ----
    h8v qf0 = *(const h8v*)(qrow + quad * 8);
    h8v qf1 = *(const h8v*)(qrow + 32 + quad * 8);
    {
      f4v H[8];
      #pragma unroll
      for (int f = 0; f < 8; ++f) H[f] = fz;
      #pragma unroll
      for (int ks = 0; ks < 6; ++ks) {
        const int k0 = ks * 32 + quad * 8;
        h8v a = (ks == 0) ? qf0 : (ks == 1) ? qf1
                 : *(const h8v*)&P_s[l15 * 136 + (k0 - 64)];
        #pragma unroll
        for (int f = 0; f < 8; ++f) {
          h8v b = *(const h8v*)(c1F + (size_t)((f * 6 + ks) * 64 + lane) * 8);
          H[f] = MFMA16(a, b, H[f]);
        }
      }
      #pragma unroll
      for (int f = 0; f < 8; ++f) {
        float bb = c1_b[f * 16 + l15];
        #pragma unroll
        for (int r = 0; r < 4; ++r)
          P_s[(quad * 4 + r) * 136 + f * 16 + l15] =
              (_Float16)fmaxf(0.f, H[f][r] + bb);
      }
    }

    // ---- c2: relu(h1 @ c2_W + b) -> h2 ----
    {
      f4v G[4];
      #pragma unroll
      for (int f = 0; f < 4; ++f) G[f] = fz;
      #pragma unroll
      for (int ks = 0; ks < 4; ++ks) {
        const int k0 = ks * 32 + quad * 8;
        h8v a = *(const h8v*)&P_s[l15 * 136 + k0];
        #pragma unroll
        for (int f = 0; f < 4; ++f) {
          h8v b = *(const h8v*)(c2F + (size_t)((f * 4 + ks) * 64 + lane) * 8);
          G[f] = MFMA16(a, b, G[f]);
        }
      }
      #pragma unroll
      for (int f = 0; f < 4; ++f) {
        float bb = c2_b[f * 16 + l15];
        #pragma unroll
        for (int r = 0; r < 4; ++r)
          h2_s[(quad * 4 + r) * 72 + f * 16 + l15] =
              (_Float16)fmaxf(0.f, G[f][r] + bb);
      }
    }

    // ---- c3 + loss (4 lanes per query row) ----
    {
      const int prow = lane >> 2, pj = lane & 3;
      float s = 0.f;
      #pragma unroll
      for (int k = 0; k < 16; ++k) {
        int kk = pj * 16 + k;
        s += (float)h2_s[prow * 72 + kk] * c3W[kk];
      }
      s += __shfl_xor(s, 1);
      s += __shfl_xor(s, 2);
      float pred = s + c3b[0];
      float diff = pred - qy[r0 + prow];
      if (pj == 0) out_pred[r0 + prow] = pred;
      lsum += diff * diff;                      // each row counted 4x
    }
  }

  // one atomic per block
  #pragma unroll
  for (int m = 1; m < 64; m <<= 1) lsum += __shfl_xor(lsum, m);
  if (lane == 0) atomicAdd(dout, lsum * (1.0f / (4.0f * (float)BQ)));
}

// ---------------------------------------------------------------------------
extern "C" void kernel_launch(void* const* d_in, const int* in_sizes, int n_in,
                              void* d_out, int out_size, void* d_ws, size_t ws_size,
                              hipStream_t stream)
{
  const float* support_x = (const float*)d_in[0];
  const float* support_y = (const float*)d_in[1];
  const float* query_x   = (const float*)d_in[2];
  const float* query_y   = (const float*)d_in[3];
  const float* base_W    = (const float*)d_in[4];
  const float* base_b    = (const float*)d_in[5];
  const float* kp_W      = (const float*)d_in[6];
  const float* kp_b      = (const float*)d_in[7];
  const float* vp_W      = (const float*)d_in[8];
  const float* vp_b      = (const float*)d_in[9];
  const float* mem_keys  = (const float*)d_in[10];
  const float* mem_vals  = (const float*)d_in[11];
  const float* mem_age   = (const float*)d_in[12];
  const float* c1_W      = (const float*)d_in[13];
  const float* c1_b      = (const float*)d_in[14];
  const float* c2_W      = (const float*)d_in[15];
  const float* c2_b      = (const float*)d_in[16];
  const float* c3_W      = (const float*)d_in[17];
  const float* c3_b      = (const float*)d_in[18];

  char* w = (char*)d_ws;                        // ~17.8 MB used
  _Float16* WTf   = (_Float16*)(w + 0);         // 128 KB fragment-major
  _Float16* vpWt  = (_Float16*)(w + 131072);    // 32 KB
  _Float16* c1F   = (_Float16*)(w + 163840);    // 48 KB fragment-major
  _Float16* c2F   = (_Float16*)(w + 212992);    // 16 KB fragment-major
  float*    bcomb = (float*)   (w + 229376);    // 512 B
  int*      ranks = (int*)     (w + 229888);    // 4 KB
  float*    pkeys = (float*)   (w + 233984);    // 128 KB
  float*    pvals = (float*)   (w + 365056);    // 256 KB
  _Float16* keysF = (_Float16*)(w + 627200);    // 128 KB fragment-major
  _Float16* valF  = (_Float16*)(w + 758272);    // 256 KB fragment-major
  _Float16* qfpq  = (_Float16*)(w + 1048576);   // 16 MB

  float* out = (float*)d_out;

  hipLaunchKernelGGL(k_prep1, dim3(453), dim3(256), 0, stream,
                     base_W, base_b, kp_W, kp_b, vp_W, c1_W, c2_W, mem_age,
                     WTf, bcomb, vpWt, c1F, c2F, ranks, out);
  hipLaunchKernelGGL(k_prep2, dim3(64), dim3(64), 0, stream,
                     support_x, support_y, WTf, bcomb, vpWt, vp_b, pkeys, pvals);
  hipLaunchKernelGGL(k_prep3, dim3(768), dim3(256), 0, stream,
                     ranks, pkeys, pvals, mem_keys, mem_vals, keysF, valF);
  hipLaunchKernelGGL(k_feat, dim3(BQ / 32), dim3(64), 0, stream,
                     query_x, WTf, bcomb, qfpq);
  hipLaunchKernelGGL(k_main, dim3(BQ / 32), dim3(64), 0, stream,
                     qfpq, query_y, c1_b, c2_b, c3_W, c3_b,
                     c1F, c2F, keysF, valF, out);
}

// Round 5
// 483.690 us; speedup vs baseline: 1.1793x; 1.1551x over previous
//
#include <hip/hip_runtime.h>

typedef _Float16 h8v __attribute__((ext_vector_type(8)));
typedef _Float16 h4v __attribute__((ext_vector_type(4)));
typedef float    f4v __attribute__((ext_vector_type(4)));

#define MFMA16(a,b,c) __builtin_amdgcn_mfma_f32_16x16x32_f16((a),(b),(c),0,0,0)
#define NEGF (-1e30f)

#define MEM 1000
#define KEY 64
#define VAL 128
#define DIN 512
#define BS  512
#define BQ  65536

// Fragment-major B layouts: element (F,KS,lane,j) at ((F*nKS+KS)*64+lane)*8+j
// holds B[n = F*16 + (lane&15)][k = KS*32 + (lane>>4)*8 + j]  -> every MFMA
// B-fragment load is lane-contiguous (16 B/lane, 1 KB/wave, 8 full lines).
// qfpq is A-fragment-major: tile t (16 queries), frag KS in 0..3 (k=KS*32..):
// offset ((t*4+KS)*64+lane)*8 ; KS 0,1 = qf cols, KS 2,3 = pq cols.

__device__ __forceinline__ h8v cvt8(const float* p)
{
  f4v u = *(const f4v*)p;
  f4v v = *(const f4v*)(p + 4);
  h8v a;
  a[0] = (_Float16)u.x; a[1] = (_Float16)u.y; a[2] = (_Float16)u.z; a[3] = (_Float16)u.w;
  a[4] = (_Float16)v.x; a[5] = (_Float16)v.y; a[6] = (_Float16)v.z; a[7] = (_Float16)v.w;
  return a;
}

__device__ __forceinline__ h8v cvt8nt(const float* p)
{
  f4v u = __builtin_nontemporal_load((const f4v*)p);
  f4v v = __builtin_nontemporal_load((const f4v*)(p + 4));
  h8v a;
  a[0] = (_Float16)u.x; a[1] = (_Float16)u.y; a[2] = (_Float16)u.z; a[3] = (_Float16)u.w;
  a[4] = (_Float16)v.x; a[5] = (_Float16)v.y; a[6] = (_Float16)v.z; a[7] = (_Float16)v.w;
  return a;
}

// ---------------------------------------------------------------------------
// prep1: fragment-major weights, Wck = baseW@kpW fused, bcomb, ranks, zero
// ---------------------------------------------------------------------------
__global__ void k_prep1(const float* __restrict__ baseW, const float* __restrict__ base_b,
                        const float* __restrict__ kpW, const float* __restrict__ kp_b,
                        const float* __restrict__ vpW, const float* __restrict__ c1W,
                        const float* __restrict__ c2W, const float* __restrict__ age,
                        _Float16* __restrict__ WTf, float* __restrict__ bcomb,
                        _Float16* __restrict__ vpWt, _Float16* __restrict__ c1F,
                        _Float16* __restrict__ c2F, int* __restrict__ ranks,
                        float* __restrict__ out0)
{
  long id = (long)blockIdx.x * 256 + threadIdx.x;
  if (id < 65536) {                        // WTf: [baseW^T | Wck^T], n=128, k=512 (KS=16)
    int h = (int)id;
    int j = h & 7, lane = (h >> 3) & 63, KS = (h >> 9) & 15, F = h >> 13;
    int n = F * 16 + (lane & 15);
    int k = KS * 32 + ((lane >> 4) << 3) + j;
    float v;
    if (n < 64) v = baseW[(size_t)k * 64 + n];
    else {
      int nn = n - 64;
      const float* br = baseW + (size_t)k * 64;
      float s = 0.f;
      for (int t = 0; t < 64; ++t) s += br[t] * kpW[t * 64 + nn];
      v = s;
    }
    WTf[h] = (_Float16)v;
  } else if (id < 65664) {                 // bcomb
    int i = (int)(id - 65536);
    if (i < 64) bcomb[i] = base_b[i];
    else {
      int n = i - 64;
      float s = kp_b[n];
      for (int t = 0; t < 64; ++t) s += base_b[t] * kpW[t * 64 + n];
      bcomb[i] = s;
    }
  } else if (id < 90240) {                 // c1F: n=128 (F=8), k=192 (KS=6)
    int h = (int)(id - 65664);
    int j = h & 7, lane = (h >> 3) & 63, KS = (h >> 9) % 6, F = (h >> 9) / 6;
    int n = F * 16 + (lane & 15);
    int k = KS * 32 + ((lane >> 4) << 3) + j;
    c1F[h] = (_Float16)c1W[(size_t)k * 128 + n];
  } else if (id < 98432) {                 // c2F: n=64 (F=4), k=128 (KS=4)
    int h = (int)(id - 90240);
    int j = h & 7, lane = (h >> 3) & 63, KS = (h >> 9) & 3, F = h >> 11;
    int n = F * 16 + (lane & 15);
    int k = KS * 32 + ((lane >> 4) << 3) + j;
    c2F[h] = (_Float16)c2W[(size_t)k * 64 + n];
  } else if (id < 114816) {                // vpWt[n][k] (row-major transposed, prep2 only)
    long i = id - 98432;
    int n = (int)(i >> 7), k = (int)(i & 127);
    vpWt[i] = (_Float16)vpW[(size_t)k * 128 + n];
  } else if (id < 115816) {                // stable ranks (lax.top_k order)
    int jx = (int)(id - 114816);
    float aj = age[jx];
    int r = 0;
    for (int i2 = 0; i2 < MEM; ++i2) {
      float ai = age[i2];
      r += (ai > aj) || (ai == aj && i2 < jx);
    }
    ranks[jx] = r;
  } else if (id == 115816) {
    *out0 = 0.f;
  }
}

// ---------------------------------------------------------------------------
// prep2: pkeys = sx@Wck + bck ; pvals = sy@vpW + vp_b
// ---------------------------------------------------------------------------
__global__ __launch_bounds__(64) void k_prep2(
    const float* __restrict__ sx, const float* __restrict__ sy,
    const _Float16* __restrict__ WTf, const float* __restrict__ bcomb,
    const _Float16* __restrict__ vpWt, const float* __restrict__ vp_b,
    float* __restrict__ pkeys, float* __restrict__ pvals)
{
  const int lane = threadIdx.x, quad = lane >> 4, l15 = lane & 15;
  const f4v fz = {0.f, 0.f, 0.f, 0.f};
  if (blockIdx.x < 32) {
    const int m0 = blockIdx.x * 16;
    f4v acc[4];
    #pragma unroll
    for (int f = 0; f < 4; ++f) acc[f] = fz;
    const float* xr = sx + (size_t)(m0 + l15) * DIN;
    #pragma unroll 4
    for (int ks = 0; ks < 16; ++ks) {
      int k0 = ks * 32 + quad * 8;
      h8v a = cvt8(xr + k0);
      #pragma unroll
      for (int f = 0; f < 4; ++f) {
        h8v b = *(const h8v*)(WTf + (size_t)((((4 + f) * 16) + ks) * 64 + lane) * 8);
        acc[f] = MFMA16(a, b, acc[f]);
      }
    }
    #pragma unroll
    for (int f = 0; f < 4; ++f) {
      int col = f * 16 + l15;
      float bb = bcomb[64 + col];
      #pragma unroll
      for (int r = 0; r < 4; ++r)
        pkeys[(size_t)(m0 + quad * 4 + r) * KEY + col] = acc[f][r] + bb;
    }
  } else {
    const int m0 = (blockIdx.x - 32) * 16;
    f4v acc[8];
    #pragma unroll
    for (int f = 0; f < 8; ++f) acc[f] = fz;
    const float* yr = sy + (size_t)(m0 + l15) * VAL;
    #pragma unroll
    for (int ks = 0; ks < 4; ++ks) {
      int k0 = ks * 32 + quad * 8;
      h8v a = cvt8(yr + k0);
      #pragma unroll
      for (int f = 0; f < 8; ++f) {
        h8v b = *(const h8v*)(vpWt + (size_t)(f * 16 + l15) * 128 + k0);
        acc[f] = MFMA16(a, b, acc[f]);
      }
    }
    #pragma unroll
    for (int f = 0; f < 8; ++f) {
      int col = f * 16 + l15;
      float bb = vp_b[col];
      #pragma unroll
      for (int r = 0; r < 4; ++r)
        pvals[(size_t)(m0 + quad * 4 + r) * VAL + col] = acc[f][r] + bb;
    }
  }
}

// ---------------------------------------------------------------------------
// prep3: scatter memory into fragment-major keysF / valF (zero-padded)
// keysF: n=1024 slots (F=64), k=KEY 64 (KS=2)
// valF : n=VAL 128 (F=8),     k=1024 slots (KS=32)
// ---------------------------------------------------------------------------
__global__ void k_prep3(const int* __restrict__ ranks, const float* __restrict__ pk,
                        const float* __restrict__ pv, const float* __restrict__ memK,
                        const float* __restrict__ memV,
                        _Float16* __restrict__ keysF, _Float16* __restrict__ valF)
{
  int id = blockIdx.x * 256 + threadIdx.x;
  if (id < 65536) {
    int j = id & 7, lane = (id >> 3) & 63, KS = (id >> 9) & 1, F = id >> 10;
    int n = F * 16 + (lane & 15);                  // mem slot
    int k = KS * 32 + ((lane >> 4) << 3) + j;      // key col
    float v = 0.f;
    if (n < MEM) {
      int rk = ranks[n];
      v = (rk < BS) ? pk[(size_t)rk * KEY + k] : memK[(size_t)n * KEY + k];
    }
    keysF[id] = (_Float16)v;
  } else {
    int h = id - 65536;
    int j = h & 7, lane = (h >> 3) & 63, KS = (h >> 9) & 31, F = h >> 14;
    int nv = F * 16 + (lane & 15);                 // val col
    int jm = KS * 32 + ((lane >> 4) << 3) + j;     // mem slot
    float v = 0.f;
    if (jm < MEM) {
      int rk = ranks[jm];
      v = (rk < BS) ? pv[(size_t)rk * VAL + nv] : memV[(size_t)jm * VAL + nv];
    }
    valF[h] = (_Float16)v;
  }
}

// ---------------------------------------------------------------------------
// feat: qfpq (A-frag-major) = qx @ [baseW | Wck] + bcomb. 16 rows/wave,
// grid 4096 -> 16 waves/CU. nt loads (read-once qx), nt stores.
// ---------------------------------------------------------------------------
__global__ __launch_bounds__(64, 4) void k_feat(const float* __restrict__ qx,
                                                const _Float16* __restrict__ WTf,
                                                const float* __restrict__ bcomb,
                                                _Float16* __restrict__ qfpq)
{
  __shared__ __align__(16) _Float16 tbuf[16 * 136];
  const int lane = threadIdx.x, quad = lane >> 4, l15 = lane & 15;
  const int q0 = blockIdx.x * 16;
  const f4v fz = {0.f, 0.f, 0.f, 0.f};
  f4v acc[8];
  #pragma unroll
  for (int f = 0; f < 8; ++f) acc[f] = fz;

  const float* xr = qx + (size_t)(q0 + l15) * DIN;

  #pragma unroll 4
  for (int ks = 0; ks < 16; ++ks) {
    const int k0 = ks * 32 + quad * 8;
    h8v a = cvt8nt(xr + k0);
    #pragma unroll
    for (int f = 0; f < 8; ++f) {
      h8v b = *(const h8v*)(WTf + (size_t)((f * 16 + ks) * 64 + lane) * 8);
      acc[f] = MFMA16(a, b, acc[f]);
    }
  }
  // C-layout -> LDS -> A-frag-major contiguous nt stores
  #pragma unroll
  for (int f = 0; f < 8; ++f) {
    float bb = bcomb[f * 16 + l15];
    #pragma unroll
    for (int r = 0; r < 4; ++r)
      tbuf[(quad * 4 + r) * 136 + f * 16 + l15] = (_Float16)(acc[f][r] + bb);
  }
  const size_t ob = (size_t)blockIdx.x * 4 * 512;
  #pragma unroll
  for (int KS = 0; KS < 4; ++KS) {
    h8v v = *(const h8v*)&tbuf[l15 * 136 + KS * 32 + quad * 8];
    __builtin_nontemporal_store(v, (h8v*)(qfpq + ob + KS * 512 + lane * 8));
  }
}

// ---------------------------------------------------------------------------
// main: fused attention + controller. 16 queries/wave, grid 4096 (16 waves/CU).
// Chunk-pair ILP (S0/S1), per-lane softmax partial sums (one reduce at end),
// contiguous nt out_ret stores from LDS. launch_bounds(64,4): 128-VGPR cap.
// ---------------------------------------------------------------------------
__global__ __launch_bounds__(64, 4) void k_main(
    const _Float16* __restrict__ qfpq, const float* __restrict__ qy,
    const float* __restrict__ c1_b, const float* __restrict__ c2_b,
    const float* __restrict__ c3W, const float* __restrict__ c3b,
    const _Float16* __restrict__ c1F, const _Float16* __restrict__ c2F,
    const _Float16* __restrict__ keysF, const _Float16* __restrict__ valF,
    float* __restrict__ dout)
{
  __shared__ __align__(16) char smem[6656];
  _Float16* P_s  = (_Float16*)smem;            // 16 x 136 : P / ret / h1 overlay
  _Float16* h2_s = (_Float16*)(smem + 4352);   // 16 x 72

  const int lane = threadIdx.x;
  const int quad = lane >> 4;
  const int l15  = lane & 15;
  const int q0   = blockIdx.x * 16;

  float* out_pred = dout + 1;
  float* out_ret  = dout + 1 + BQ;
  const f4v fz = {0.f, 0.f, 0.f, 0.f};

  const size_t fb = (size_t)blockIdx.x * 4 * 512;  // A-frag base (halves)
  h8v pq0 = __builtin_nontemporal_load((const h8v*)(qfpq + fb + 2 * 512 + lane * 8));
  h8v pq1 = __builtin_nontemporal_load((const h8v*)(qfpq + fb + 3 * 512 + lane * 8));

  // ---- attention: online softmax, chunk pairs for ILP ----
  float rm[4], rl[4];
  #pragma unroll
  for (int r = 0; r < 4; ++r) { rm[r] = NEGF; rl[r] = 0.f; }
  f4v O[8];
  #pragma unroll
  for (int v = 0; v < 8; ++v) O[v] = fz;

  #pragma unroll 1
  for (int cc = 0; cc < 4; ++cc) {
    const int c0 = cc * 2;
    f4v S0[8], S1[8];
    #pragma unroll
    for (int f = 0; f < 8; ++f) { S0[f] = fz; S1[f] = fz; }

    // QK for both chunks up front (32 independent MFMAs)
    #pragma unroll
    for (int f = 0; f < 8; ++f) {
      const int F = c0 * 8 + f;
      h8v b0 = *(const h8v*)(keysF + (size_t)(F * 2 + 0) * 512 + lane * 8);
      h8v b1 = *(const h8v*)(keysF + (size_t)(F * 2 + 1) * 512 + lane * 8);
      S0[f] = MFMA16(pq0, b0, S0[f]);
      S0[f] = MFMA16(pq1, b1, S0[f]);
    }
    #pragma unroll
    for (int f = 0; f < 8; ++f) {
      const int F = (c0 + 1) * 8 + f;
      h8v b0 = *(const h8v*)(keysF + (size_t)(F * 2 + 0) * 512 + lane * 8);
      h8v b1 = *(const h8v*)(keysF + (size_t)(F * 2 + 1) * 512 + lane * 8);
      S1[f] = MFMA16(pq0, b0, S1[f]);
      S1[f] = MFMA16(pq1, b1, S1[f]);
    }

    #pragma unroll
    for (int par = 0; par < 2; ++par) {
      f4v* S = par ? S1 : S0;
      const int c = c0 + par;

      float cm[4] = {NEGF, NEGF, NEGF, NEGF};
      #pragma unroll
      for (int f = 0; f < 8; ++f) {
        const int col = c * 128 + f * 16 + l15;
        const bool ok = (col < MEM);
        #pragma unroll
        for (int r = 0; r < 4; ++r) {
          float s = ok ? S[f][r] : NEGF;
          S[f][r] = s;
          cm[r] = fmaxf(cm[r], s);
        }
      }
      #pragma unroll
      for (int r = 0; r < 4; ++r) {
        #pragma unroll
        for (int m = 1; m < 16; m <<= 1) cm[r] = fmaxf(cm[r], __shfl_xor(cm[r], m));
      }
      float al[4];
      #pragma unroll
      for (int r = 0; r < 4; ++r) {
        float mn = fmaxf(rm[r], cm[r]);
        al[r] = __expf(rm[r] - mn);
        rm[r] = mn;
      }
      float psl[4] = {0.f, 0.f, 0.f, 0.f};     // per-lane partial sum (no reduce)
      #pragma unroll
      for (int f = 0; f < 8; ++f)
        #pragma unroll
        for (int r = 0; r < 4; ++r) {
          float p = __expf(S[f][r] - rm[r]);
          S[f][r] = p;
          psl[r] += p;
        }
      #pragma unroll
      for (int r = 0; r < 4; ++r) rl[r] = rl[r] * al[r] + psl[r];

      // P -> LDS (C-layout -> A-layout), rescale O, P @ V
      #pragma unroll
      for (int f = 0; f < 8; ++f)
        #pragma unroll
        for (int r = 0; r < 4; ++r)
          P_s[(quad * 4 + r) * 136 + f * 16 + l15] = (_Float16)S[f][r];
      #pragma unroll
      for (int v = 0; v < 8; ++v)
        #pragma unroll
        for (int r = 0; r < 4; ++r) O[v][r] *= al[r];
      #pragma unroll
      for (int ks = 0; ks < 4; ++ks) {
        h8v a = *(const h8v*)&P_s[l15 * 136 + ks * 32 + quad * 8];
        #pragma unroll
        for (int v = 0; v < 8; ++v) {
          h8v b = *(const h8v*)(valF + (size_t)(v * 32 + c * 4 + ks) * 512 + lane * 8);
          O[v] = MFMA16(a, b, O[v]);
        }
      }
    }
  }

  // ---- final denominator: one cross-lane reduce ----
  #pragma unroll
  for (int r = 0; r < 4; ++r) {
    #pragma unroll
    for (int m = 1; m < 16; m <<= 1) rl[r] += __shfl_xor(rl[r], m);
  }

  // ---- retrieved -> LDS fp16 (P dead -> ret) ----
  #pragma unroll
  for (int v = 0; v < 8; ++v)
    #pragma unroll
    for (int r = 0; r < 4; ++r)
      P_s[(quad * 4 + r) * 136 + v * 16 + l15] = (_Float16)(O[v][r] / rl[r]);

  // contiguous nt stores: 8 iters x (64 lanes x 16 B) = full lines
  #pragma unroll
  for (int it = 0; it < 8; ++it) {
    int flat = it * 256 + lane * 4;            // element within 16x128 tile
    int row = flat >> 7, col = flat & 127;
    h4v t = *(const h4v*)&P_s[row * 136 + col];
    f4v o;
    o.x = (float)t[0]; o.y = (float)t[1]; o.z = (float)t[2]; o.w = (float)t[3];
    __builtin_nontemporal_store(o, (f4v*)(out_ret + (size_t)q0 * VAL + flat));
  }

  // ---- c1: relu([qf|ret] @ c1_W + b); h1 overwrites ret in place ----
  h8v qf0 = __builtin_nontemporal_load((const h8v*)(qfpq + fb + 0 * 512 + lane * 8));
  h8v qf1 = __builtin_nontemporal_load((const h8v*)(qfpq + fb + 1 * 512 + lane * 8));
  {
    f4v H[8];
    #pragma unroll
    for (int f = 0; f < 8; ++f) H[f] = fz;
    #pragma unroll
    for (int ks = 0; ks < 6; ++ks) {
      const int k0 = ks * 32;
      h8v a = (ks == 0) ? qf0 : (ks == 1) ? qf1
               : *(const h8v*)&P_s[l15 * 136 + (k0 - 64) + quad * 8];
      #pragma unroll
      for (int f = 0; f < 8; ++f) {
        h8v b = *(const h8v*)(c1F + (size_t)(f * 6 + ks) * 512 + lane * 8);
        H[f] = MFMA16(a, b, H[f]);
      }
    }
    #pragma unroll
    for (int f = 0; f < 8; ++f) {
      float bb = c1_b[f * 16 + l15];
      #pragma unroll
      for (int r = 0; r < 4; ++r)
        P_s[(quad * 4 + r) * 136 + f * 16 + l15] =
            (_Float16)fmaxf(0.f, H[f][r] + bb);
    }
  }

  // ---- c2: relu(h1 @ c2_W + b) -> h2 ----
  {
    f4v G[4];
    #pragma unroll
    for (int f = 0; f < 4; ++f) G[f] = fz;
    #pragma unroll
    for (int ks = 0; ks < 4; ++ks) {
      h8v a = *(const h8v*)&P_s[l15 * 136 + ks * 32 + quad * 8];
      #pragma unroll
      for (int f = 0; f < 4; ++f) {
        h8v b = *(const h8v*)(c2F + (size_t)(f * 4 + ks) * 512 + lane * 8);
        G[f] = MFMA16(a, b, G[f]);
      }
    }
    #pragma unroll
    for (int f = 0; f < 4; ++f) {
      float bb = c2_b[f * 16 + l15];
      #pragma unroll
      for (int r = 0; r < 4; ++r)
        h2_s[(quad * 4 + r) * 72 + f * 16 + l15] =
            (_Float16)fmaxf(0.f, G[f][r] + bb);
    }
  }

  // ---- c3 + loss (4 lanes per query row) ----
  float lsum;
  {
    const int prow = lane >> 2, pj = lane & 3;
    float s = 0.f;
    #pragma unroll
    for (int k = 0; k < 16; ++k) {
      int kk = pj * 16 + k;
      s += (float)h2_s[prow * 72 + kk] * c3W[kk];
    }
    s += __shfl_xor(s, 1);
    s += __shfl_xor(s, 2);
    float pred = s + c3b[0];
    float diff = pred - qy[q0 + prow];
    if (pj == 0) out_pred[q0 + prow] = pred;
    lsum = diff * diff;                        // each row counted 4x
  }
  #pragma unroll
  for (int m = 1; m < 64; m <<= 1) lsum += __shfl_xor(lsum, m);
  if (lane == 0) atomicAdd(dout, lsum * (1.0f / (4.0f * (float)BQ)));
}

// ---------------------------------------------------------------------------
extern "C" void kernel_launch(void* const* d_in, const int* in_sizes, int n_in,
                              void* d_out, int out_size, void* d_ws, size_t ws_size,
                              hipStream_t stream)
{
  const float* support_x = (const float*)d_in[0];
  const float* support_y = (const float*)d_in[1];
  const float* query_x   = (const float*)d_in[2];
  const float* query_y   = (const float*)d_in[3];
  const float* base_W    = (const float*)d_in[4];
  const float* base_b    = (const float*)d_in[5];
  const float* kp_W      = (const float*)d_in[6];
  const float* kp_b      = (const float*)d_in[7];
  const float* vp_W      = (const float*)d_in[8];
  const float* vp_b      = (const float*)d_in[9];
  const float* mem_keys  = (const float*)d_in[10];
  const float* mem_vals  = (const float*)d_in[11];
  const float* mem_age   = (const float*)d_in[12];
  const float* c1_W      = (const float*)d_in[13];
  const float* c1_b      = (const float*)d_in[14];
  const float* c2_W      = (const float*)d_in[15];
  const float* c2_b      = (const float*)d_in[16];
  const float* c3_W      = (const float*)d_in[17];
  const float* c3_b      = (const float*)d_in[18];

  char* w = (char*)d_ws;                        // ~17.8 MB used
  _Float16* WTf   = (_Float16*)(w + 0);         // 128 KB fragment-major
  _Float16* vpWt  = (_Float16*)(w + 131072);    // 32 KB
  _Float16* c1F   = (_Float16*)(w + 163840);    // 48 KB fragment-major
  _Float16* c2F   = (_Float16*)(w + 212992);    // 16 KB fragment-major
  float*    bcomb = (float*)   (w + 229376);    // 512 B
  int*      ranks = (int*)     (w + 229888);    // 4 KB
  float*    pkeys = (float*)   (w + 233984);    // 128 KB
  float*    pvals = (float*)   (w + 365056);    // 256 KB
  _Float16* keysF = (_Float16*)(w + 627200);    // 128 KB fragment-major
  _Float16* valF  = (_Float16*)(w + 758272);    // 256 KB fragment-major
  _Float16* qfpq  = (_Float16*)(w + 1048576);   // 16 MB A-frag-major

  float* out = (float*)d_out;

  hipLaunchKernelGGL(k_prep1, dim3(453), dim3(256), 0, stream,
                     base_W, base_b, kp_W, kp_b, vp_W, c1_W, c2_W, mem_age,
                     WTf, bcomb, vpWt, c1F, c2F, ranks, out);
  hipLaunchKernelGGL(k_prep2, dim3(64), dim3(64), 0, stream,
                     support_x, support_y, WTf, bcomb, vpWt, vp_b, pkeys, pvals);
  hipLaunchKernelGGL(k_prep3, dim3(768), dim3(256), 0, stream,
                     ranks, pkeys, pvals, mem_keys, mem_vals, keysF, valF);
  hipLaunchKernelGGL(k_feat, dim3(BQ / 16), dim3(64), 0, stream,
                     query_x, WTf, bcomb, qfpq);
  hipLaunchKernelGGL(k_main, dim3(BQ / 16), dim3(64), 0, stream,
                     qfpq, query_y, c1_b, c2_b, c3_W, c3_b,
                     c1F, c2F, keysF, valF, out);
}